// Round 3
// baseline (615.857 us; speedup 1.0000x reference)
//
#include <hip/hip_runtime.h>
#include <math.h>

#define NUM_GRAPHS 1024
#define NUM_FEAT 128
#define EPS 1e-5f
#define ROWS_PER_BLOCK 128   // 256 thr = 8 row-groups x 16 rows
#define NCHUNK 8

typedef float f4 __attribute__((ext_vector_type(4)));

// ws layout (floats): [0,1024) gsum | [1024,2048) gss | [2048,3072) gcnt(int)
__global__ void zero_ws_kernel(float* ws) {
    int i = blockIdx.x * blockDim.x + threadIdx.x;
    if (i < 3 * NUM_GRAPHS) ws[i] = 0.0f;  // zero bits also zero the int counts
}

__global__ void pass1_kernel(const float* __restrict__ x,
                             const int* __restrict__ batch,
                             float* __restrict__ gsum,
                             float* __restrict__ gss,
                             int* __restrict__ gcnt,
                             int r_begin, int r_end) {
    int r0 = r_begin + blockIdx.x * ROWS_PER_BLOCK;
    if (r0 >= r_end) return;
    int r1 = min(r0 + ROWS_PER_BLOCK, r_end);

    const int lane32  = threadIdx.x & 31;   // 32 lanes per row (128 floats = 32 f4)
    const int rowgrp  = threadIdx.x >> 5;   // 0..7
    const int nrowgrp = blockDim.x >> 5;    // 8

    // batch is sorted: accumulate in registers until the graph id changes,
    // then flush (shfl reduce + 3 global atomics). ~1-2 flushes per group.
    float s = 0.0f, ss = 0.0f;
    int cnt = 0, cur_g = -1;

    for (int r = r0 + rowgrp; r < r1; r += nrowgrp) {
        int g = batch[r];  // uniform across the 32-lane group
        if (g != cur_g) {
            if (cnt > 0) {
                float ts = s, tss = ss;
                #pragma unroll
                for (int off = 16; off > 0; off >>= 1) {
                    ts  += __shfl_down(ts,  off, 32);
                    tss += __shfl_down(tss, off, 32);
                }
                if (lane32 == 0) {
                    atomicAdd(&gsum[cur_g], ts);
                    atomicAdd(&gss[cur_g],  tss);
                    atomicAdd(&gcnt[cur_g], cnt);
                }
            }
            s = 0.0f; ss = 0.0f; cnt = 0; cur_g = g;
        }
        const f4 v = reinterpret_cast<const f4*>(x + (size_t)r * NUM_FEAT)[lane32];
        s += v.x + v.y + v.z + v.w;
        ss = fmaf(v.x, v.x, fmaf(v.y, v.y, fmaf(v.z, v.z, fmaf(v.w, v.w, ss))));
        cnt += 1;
    }
    if (cnt > 0) {
        float ts = s, tss = ss;
        #pragma unroll
        for (int off = 16; off > 0; off >>= 1) {
            ts  += __shfl_down(ts,  off, 32);
            tss += __shfl_down(tss, off, 32);
        }
        if (lane32 == 0) {
            atomicAdd(&gsum[cur_g], ts);
            atomicAdd(&gss[cur_g],  tss);
            atomicAdd(&gcnt[cur_g], cnt);
        }
    }
}

// Row-wise normalize. Runs one chunk BEHIND pass1 so stats of any graph
// straddling the chunk boundary are complete. x reads hit L3 (chunk was
// just streamed by pass1). Stats recomputed per row, amortized over 32 lanes.
__global__ void pass2_kernel(const float* __restrict__ x,
                             const int* __restrict__ batch,
                             const float* __restrict__ weight,
                             const float* __restrict__ bias,
                             const float* __restrict__ gsum,
                             const float* __restrict__ gss,
                             const int* __restrict__ gcnt,
                             float* __restrict__ out,
                             int r_begin, int r_end) {
    int r0 = r_begin + blockIdx.x * ROWS_PER_BLOCK;
    if (r0 >= r_end) return;
    int r1 = min(r0 + ROWS_PER_BLOCK, r_end);

    const int lane32  = threadIdx.x & 31;
    const int rowgrp  = threadIdx.x >> 5;
    const int nrowgrp = blockDim.x >> 5;

    const f4 w = reinterpret_cast<const f4*>(weight)[lane32];
    const f4 b = reinterpret_cast<const f4*>(bias)[lane32];

    for (int r = r0 + rowgrp; r < r1; r += nrowgrp) {
        int g = batch[r];
        float denom = fmaxf((float)gcnt[g] * (float)NUM_FEAT, 1.0f);
        float mean = gsum[g] / denom;
        float var  = fmaxf(gss[g] / denom - mean * mean, 0.0f);
        float inv  = rsqrtf(var + EPS);

        const f4 v = reinterpret_cast<const f4*>(x + (size_t)r * NUM_FEAT)[lane32];
        f4 o;
        o.x = fmaf(w.x, (v.x - mean) * inv, b.x);
        o.y = fmaf(w.y, (v.y - mean) * inv, b.y);
        o.z = fmaf(w.z, (v.z - mean) * inv, b.z);
        o.w = fmaf(w.w, (v.w - mean) * inv, b.w);
        __builtin_nontemporal_store(o, &reinterpret_cast<f4*>(out + (size_t)r * NUM_FEAT)[lane32]);
    }
}

static inline void launch_p1(const float* x, const int* batch, float* gsum, float* gss,
                             int* gcnt, int rb, int re, hipStream_t stream) {
    if (rb >= re) return;
    int blocks = (re - rb + ROWS_PER_BLOCK - 1) / ROWS_PER_BLOCK;
    pass1_kernel<<<blocks, 256, 0, stream>>>(x, batch, gsum, gss, gcnt, rb, re);
}

static inline void launch_p2(const float* x, const int* batch, const float* weight,
                             const float* bias, const float* gsum, const float* gss,
                             const int* gcnt, float* out, int rb, int re,
                             hipStream_t stream) {
    if (rb >= re) return;
    int blocks = (re - rb + ROWS_PER_BLOCK - 1) / ROWS_PER_BLOCK;
    pass2_kernel<<<blocks, 256, 0, stream>>>(x, batch, weight, bias, gsum, gss, gcnt,
                                             out, rb, re);
}

extern "C" void kernel_launch(void* const* d_in, const int* in_sizes, int n_in,
                              void* d_out, int out_size, void* d_ws, size_t ws_size,
                              hipStream_t stream) {
    const float* x      = (const float*)d_in[0];
    const int*   batch  = (const int*)d_in[1];
    const float* weight = (const float*)d_in[2];
    const float* bias   = (const float*)d_in[3];
    float* out = (float*)d_out;

    const int n_rows = in_sizes[1];  // NUM_NODES

    float* ws   = (float*)d_ws;
    float* gsum = ws;
    float* gss  = ws + NUM_GRAPHS;
    int*   gcnt = (int*)(ws + 2 * NUM_GRAPHS);

    zero_ws_kernel<<<(3 * NUM_GRAPHS + 255) / 256, 256, 0, stream>>>(ws);

    const int rpc = (n_rows + NCHUNK - 1) / NCHUNK;  // rows per chunk
    auto cb = [&](int k) { return min(k * rpc, n_rows); };

    // pipeline: p1_0, p1_1, p2_0, p1_2, p2_1, ... p1_{n-1}, p2_{n-2}, p2_{n-1}
    launch_p1(x, batch, gsum, gss, gcnt, cb(0), cb(1), stream);
    for (int k = 1; k < NCHUNK; ++k) {
        launch_p1(x, batch, gsum, gss, gcnt, cb(k), cb(k + 1), stream);
        launch_p2(x, batch, weight, bias, gsum, gss, gcnt, out, cb(k - 1), cb(k), stream);
    }
    launch_p2(x, batch, weight, bias, gsum, gss, gcnt, out, cb(NCHUNK - 1), cb(NCHUNK), stream);
}

// Round 4
// 335.559 us; speedup vs baseline: 1.8353x; 1.8353x over previous
//
#include <hip/hip_runtime.h>
#include <math.h>

#define NUM_GRAPHS 1024
#define NUM_FEAT 128
#define EPS 1e-5f
#define NB 256     // grid of fused kernel: ~1 block/CU; L3 footprint = NB * ~0.5MB
#define BT 512     // threads per block = 16 row-groups of 32 lanes

typedef float f4 __attribute__((ext_vector_type(4)));

// ws layout (ints): [0,1024) gstart | [1024,2048) gend
__global__ void init_bounds_kernel(int* gstart, int* gend) {
    int g = blockIdx.x * blockDim.x + threadIdx.x;
    if (g < NUM_GRAPHS) { gstart[g] = 0; gend[g] = 0; }  // empty graphs -> [0,0)
}

__global__ void find_bounds_kernel(const int* __restrict__ batch, int n_rows,
                                   int* __restrict__ gstart, int* __restrict__ gend) {
    int r = blockIdx.x * blockDim.x + threadIdx.x;
    if (r >= n_rows) return;
    int g = batch[r];
    if (r == 0 || batch[r - 1] != g) gstart[g] = r;
    if (r == n_rows - 1 || batch[r + 1] != g) gend[g] = r + 1;
}

// Block-per-graph fused stats+normalize. batch sorted => graph g is rows
// [gstart[g], gend[g]). First sweep computes sum/sumsq; second sweep re-reads
// x (L3-resident: reuse distance = one ~0.5MB graph x NB blocks = 128MB < 256MB)
// and writes out nontemporally so the write stream doesn't evict x.
__global__ __launch_bounds__(BT)
void fused_kernel(const float* __restrict__ x,
                  const float* __restrict__ weight,
                  const float* __restrict__ bias,
                  const int* __restrict__ gstart,
                  const int* __restrict__ gend,
                  float* __restrict__ out) {
    __shared__ float lsum, lss;
    __shared__ float smean, sinv;

    const int lane32 = threadIdx.x & 31;   // 32 lanes x f4 = one 128-float row
    const int grp    = threadIdx.x >> 5;   // 0..15
    const int ngrp   = BT >> 5;            // 16

    const f4 w = reinterpret_cast<const f4*>(weight)[lane32];
    const f4 b = reinterpret_cast<const f4*>(bias)[lane32];

    for (int g = blockIdx.x; g < NUM_GRAPHS; g += gridDim.x) {
        const int s = gstart[g];
        const int e = gend[g];
        if (s >= e) continue;  // g uniform across block -> no divergence hazard

        if (threadIdx.x == 0) { lsum = 0.0f; lss = 0.0f; }
        __syncthreads();

        // ---- sweep 1: accumulate sum / sumsq ----
        float as = 0.0f, ass = 0.0f;
        for (int r = s + grp; r < e; r += ngrp) {
            const f4 v = reinterpret_cast<const f4*>(x + (size_t)r * NUM_FEAT)[lane32];
            as += v.x + v.y + v.z + v.w;
            ass = fmaf(v.x, v.x, fmaf(v.y, v.y, fmaf(v.z, v.z, fmaf(v.w, v.w, ass))));
        }
        #pragma unroll
        for (int off = 16; off > 0; off >>= 1) {
            as  += __shfl_down(as,  off, 32);
            ass += __shfl_down(ass, off, 32);
        }
        if (lane32 == 0) {
            atomicAdd(&lsum, as);
            atomicAdd(&lss,  ass);
        }
        __syncthreads();

        if (threadIdx.x == 0) {
            float denom = (float)(e - s) * (float)NUM_FEAT;  // e>s => >=128
            float mean  = lsum / denom;
            float var   = fmaxf(lss / denom - mean * mean, 0.0f);
            smean = mean;
            sinv  = rsqrtf(var + EPS);
        }
        __syncthreads();

        const float mean = smean;
        const float inv  = sinv;

        // ---- sweep 2: normalize (x re-read hits L3) ----
        for (int r = s + grp; r < e; r += ngrp) {
            const f4 v = reinterpret_cast<const f4*>(x + (size_t)r * NUM_FEAT)[lane32];
            f4 o;
            o.x = fmaf(w.x, (v.x - mean) * inv, b.x);
            o.y = fmaf(w.y, (v.y - mean) * inv, b.y);
            o.z = fmaf(w.z, (v.z - mean) * inv, b.z);
            o.w = fmaf(w.w, (v.w - mean) * inv, b.w);
            __builtin_nontemporal_store(
                o, &reinterpret_cast<f4*>(out + (size_t)r * NUM_FEAT)[lane32]);
        }
        __syncthreads();  // protect lsum/lss reset of next iteration
    }
}

extern "C" void kernel_launch(void* const* d_in, const int* in_sizes, int n_in,
                              void* d_out, int out_size, void* d_ws, size_t ws_size,
                              hipStream_t stream) {
    const float* x      = (const float*)d_in[0];
    const int*   batch  = (const int*)d_in[1];
    const float* weight = (const float*)d_in[2];
    const float* bias   = (const float*)d_in[3];
    float* out = (float*)d_out;

    const int n_rows = in_sizes[1];  // NUM_NODES

    int* gstart = (int*)d_ws;
    int* gend   = gstart + NUM_GRAPHS;

    init_bounds_kernel<<<(NUM_GRAPHS + 255) / 256, 256, 0, stream>>>(gstart, gend);
    find_bounds_kernel<<<(n_rows + 255) / 256, 256, 0, stream>>>(batch, n_rows,
                                                                 gstart, gend);
    fused_kernel<<<NB, BT, 0, stream>>>(x, weight, bias, gstart, gend, out);
}

// Round 5
// 242.207 us; speedup vs baseline: 2.5427x; 1.3854x over previous
//
#include <hip/hip_runtime.h>
#include <math.h>

#define NUM_GRAPHS 1024
#define NUM_FEAT 128
#define EPS 1e-5f
#define NB 256     // 1 block/CU; concurrent-graph L3 footprint = 256 * ~0.5MB = 128MB
#define BT 1024    // 32 row-groups of 32 lanes; 16 waves/CU

typedef float f4 __attribute__((ext_vector_type(4)));

// ws layout (ints): [0,1024) gstart | [1024,2048) gend
__global__ void init_bounds_kernel(int* gstart, int* gend) {
    int g = blockIdx.x * blockDim.x + threadIdx.x;
    if (g < NUM_GRAPHS) { gstart[g] = 0; gend[g] = 0; }  // empty graphs -> [0,0)
}

__global__ void find_bounds_kernel(const int* __restrict__ batch, int n_rows,
                                   int* __restrict__ gstart, int* __restrict__ gend) {
    int r = blockIdx.x * blockDim.x + threadIdx.x;
    if (r >= n_rows) return;
    int g = batch[r];
    if (r == 0 || batch[r - 1] != g) gstart[g] = r;
    if (r == n_rows - 1 || batch[r + 1] != g) gend[g] = r + 1;
}

#define LOADX(r) (reinterpret_cast<const f4*>(x + (size_t)(r) * NUM_FEAT)[lane32])

// Block-per-graph fused stats+normalize, 4x unrolled for memory-level
// parallelism. Sweep-2's x re-read is served by L3 (confirmed round 4:
// FETCH ~= 1x x-size). Nontemporal out-stores keep x resident.
__global__ __launch_bounds__(BT)
void fused_kernel(const float* __restrict__ x,
                  const float* __restrict__ weight,
                  const float* __restrict__ bias,
                  const int* __restrict__ gstart,
                  const int* __restrict__ gend,
                  float* __restrict__ out) {
    __shared__ float lsum, lss;
    __shared__ float smean, sinv;

    const int lane32 = threadIdx.x & 31;   // 32 lanes x f4 = one 128-float row
    const int grp    = threadIdx.x >> 5;   // 0..31
    const int ngrp   = BT >> 5;            // 32

    const f4 w = reinterpret_cast<const f4*>(weight)[lane32];
    const f4 b = reinterpret_cast<const f4*>(bias)[lane32];

    for (int g = blockIdx.x; g < NUM_GRAPHS; g += gridDim.x) {
        const int s = gstart[g];
        const int e = gend[g];
        if (s >= e) continue;  // uniform across block

        if (threadIdx.x == 0) { lsum = 0.0f; lss = 0.0f; }
        __syncthreads();

        // ---- sweep 1: sum / sumsq, 4 rows in flight per group ----
        float as0 = 0.0f, ass0 = 0.0f, as1 = 0.0f, ass1 = 0.0f;
        int r = s + grp;
        for (; r + 3 * ngrp < e; r += 4 * ngrp) {
            const f4 v0 = LOADX(r);
            const f4 v1 = LOADX(r + ngrp);
            const f4 v2 = LOADX(r + 2 * ngrp);
            const f4 v3 = LOADX(r + 3 * ngrp);
            as0 += v0.x + v0.y + v0.z + v0.w;
            ass0 = fmaf(v0.x, v0.x, fmaf(v0.y, v0.y, fmaf(v0.z, v0.z, fmaf(v0.w, v0.w, ass0))));
            as1 += v1.x + v1.y + v1.z + v1.w;
            ass1 = fmaf(v1.x, v1.x, fmaf(v1.y, v1.y, fmaf(v1.z, v1.z, fmaf(v1.w, v1.w, ass1))));
            as0 += v2.x + v2.y + v2.z + v2.w;
            ass0 = fmaf(v2.x, v2.x, fmaf(v2.y, v2.y, fmaf(v2.z, v2.z, fmaf(v2.w, v2.w, ass0))));
            as1 += v3.x + v3.y + v3.z + v3.w;
            ass1 = fmaf(v3.x, v3.x, fmaf(v3.y, v3.y, fmaf(v3.z, v3.z, fmaf(v3.w, v3.w, ass1))));
        }
        for (; r < e; r += ngrp) {
            const f4 v = LOADX(r);
            as0 += v.x + v.y + v.z + v.w;
            ass0 = fmaf(v.x, v.x, fmaf(v.y, v.y, fmaf(v.z, v.z, fmaf(v.w, v.w, ass0))));
        }
        float as = as0 + as1, ass = ass0 + ass1;
        #pragma unroll
        for (int off = 16; off > 0; off >>= 1) {
            as  += __shfl_down(as,  off, 32);
            ass += __shfl_down(ass, off, 32);
        }
        if (lane32 == 0) {
            atomicAdd(&lsum, as);
            atomicAdd(&lss,  ass);
        }
        __syncthreads();

        if (threadIdx.x == 0) {
            float denom = (float)(e - s) * (float)NUM_FEAT;
            float mean  = lsum / denom;
            float var   = fmaxf(lss / denom - mean * mean, 0.0f);
            smean = mean;
            sinv  = rsqrtf(var + EPS);
        }
        __syncthreads();

        const float mean = smean;
        const float inv  = sinv;

        // ---- sweep 2: normalize (x from L3), 4 rows in flight ----
        r = s + grp;
        for (; r + 3 * ngrp < e; r += 4 * ngrp) {
            const f4 v0 = LOADX(r);
            const f4 v1 = LOADX(r + ngrp);
            const f4 v2 = LOADX(r + 2 * ngrp);
            const f4 v3 = LOADX(r + 3 * ngrp);
            f4 o0, o1, o2, o3;
            o0.x = fmaf(w.x, (v0.x - mean) * inv, b.x);
            o0.y = fmaf(w.y, (v0.y - mean) * inv, b.y);
            o0.z = fmaf(w.z, (v0.z - mean) * inv, b.z);
            o0.w = fmaf(w.w, (v0.w - mean) * inv, b.w);
            o1.x = fmaf(w.x, (v1.x - mean) * inv, b.x);
            o1.y = fmaf(w.y, (v1.y - mean) * inv, b.y);
            o1.z = fmaf(w.z, (v1.z - mean) * inv, b.z);
            o1.w = fmaf(w.w, (v1.w - mean) * inv, b.w);
            o2.x = fmaf(w.x, (v2.x - mean) * inv, b.x);
            o2.y = fmaf(w.y, (v2.y - mean) * inv, b.y);
            o2.z = fmaf(w.z, (v2.z - mean) * inv, b.z);
            o2.w = fmaf(w.w, (v2.w - mean) * inv, b.w);
            o3.x = fmaf(w.x, (v3.x - mean) * inv, b.x);
            o3.y = fmaf(w.y, (v3.y - mean) * inv, b.y);
            o3.z = fmaf(w.z, (v3.z - mean) * inv, b.z);
            o3.w = fmaf(w.w, (v3.w - mean) * inv, b.w);
            __builtin_nontemporal_store(o0, &reinterpret_cast<f4*>(out + (size_t)r * NUM_FEAT)[lane32]);
            __builtin_nontemporal_store(o1, &reinterpret_cast<f4*>(out + (size_t)(r + ngrp) * NUM_FEAT)[lane32]);
            __builtin_nontemporal_store(o2, &reinterpret_cast<f4*>(out + (size_t)(r + 2 * ngrp) * NUM_FEAT)[lane32]);
            __builtin_nontemporal_store(o3, &reinterpret_cast<f4*>(out + (size_t)(r + 3 * ngrp) * NUM_FEAT)[lane32]);
        }
        for (; r < e; r += ngrp) {
            const f4 v = LOADX(r);
            f4 o;
            o.x = fmaf(w.x, (v.x - mean) * inv, b.x);
            o.y = fmaf(w.y, (v.y - mean) * inv, b.y);
            o.z = fmaf(w.z, (v.z - mean) * inv, b.z);
            o.w = fmaf(w.w, (v.w - mean) * inv, b.w);
            __builtin_nontemporal_store(o, &reinterpret_cast<f4*>(out + (size_t)r * NUM_FEAT)[lane32]);
        }
        __syncthreads();  // protect lsum/lss reset of next graph
    }
}

extern "C" void kernel_launch(void* const* d_in, const int* in_sizes, int n_in,
                              void* d_out, int out_size, void* d_ws, size_t ws_size,
                              hipStream_t stream) {
    const float* x      = (const float*)d_in[0];
    const int*   batch  = (const int*)d_in[1];
    const float* weight = (const float*)d_in[2];
    const float* bias   = (const float*)d_in[3];
    float* out = (float*)d_out;

    const int n_rows = in_sizes[1];  // NUM_NODES

    int* gstart = (int*)d_ws;
    int* gend   = gstart + NUM_GRAPHS;

    init_bounds_kernel<<<(NUM_GRAPHS + 255) / 256, 256, 0, stream>>>(gstart, gend);
    find_bounds_kernel<<<(n_rows + 255) / 256, 256, 0, stream>>>(batch, n_rows,
                                                                 gstart, gend);
    fused_kernel<<<NB, BT, 0, stream>>>(x, weight, bias, gstart, gend, out);
}

// Round 6
// 235.718 us; speedup vs baseline: 2.6127x; 1.0275x over previous
//
#include <hip/hip_runtime.h>
#include <math.h>

#define NUM_GRAPHS 1024
#define NUM_FEAT 128
#define EPS 1e-5f
#define NB 512     // 2 blocks/CU -> 32 waves/CU; resident footprint 512 * ~0.5MB = 256MB
#define BT 1024    // 32 row-groups of 32 lanes

typedef float f4 __attribute__((ext_vector_type(4)));

// ws layout (ints): [0,1024) gstart | [1024,2048) gend
__global__ void init_bounds_kernel(int* gstart, int* gend) {
    int g = blockIdx.x * blockDim.x + threadIdx.x;
    if (g < NUM_GRAPHS) { gstart[g] = 0; gend[g] = 0; }  // empty graphs -> [0,0)
}

__global__ void find_bounds_kernel(const int* __restrict__ batch, int n_rows,
                                   int* __restrict__ gstart, int* __restrict__ gend) {
    int r = blockIdx.x * blockDim.x + threadIdx.x;
    if (r >= n_rows) return;
    int g = batch[r];
    if (r == 0 || batch[r - 1] != g) gstart[g] = r;
    if (r == n_rows - 1 || batch[r + 1] != g) gend[g] = r + 1;
}

#define LOADX(r)   (reinterpret_cast<const f4*>(x + (size_t)(r) * NUM_FEAT)[lane32])
// sweep-2 re-read: last touch of this line -> nontemporal (don't re-allocate in L3)
#define LOADX_NT(r) __builtin_nontemporal_load(&reinterpret_cast<const f4*>(x + (size_t)(r) * NUM_FEAT)[lane32])

// Block-per-graph fused stats+normalize. Sweep-2's x re-read is L3-resident
// (round-4 counters: FETCH ~= 1x x-size). NT loads on the re-read + NT stores
// on out keep L3 space for other blocks' pending sweep-1 lines.
__global__ __launch_bounds__(BT)
void fused_kernel(const float* __restrict__ x,
                  const float* __restrict__ weight,
                  const float* __restrict__ bias,
                  const int* __restrict__ gstart,
                  const int* __restrict__ gend,
                  float* __restrict__ out) {
    __shared__ float lsum, lss;

    const int lane32 = threadIdx.x & 31;   // 32 lanes x f4 = one 128-float row
    const int grp    = threadIdx.x >> 5;   // 0..31
    const int ngrp   = BT >> 5;            // 32

    const f4 w = reinterpret_cast<const f4*>(weight)[lane32];
    const f4 b = reinterpret_cast<const f4*>(bias)[lane32];

    for (int g = blockIdx.x; g < NUM_GRAPHS; g += gridDim.x) {
        const int s = gstart[g];
        const int e = gend[g];
        if (s >= e) { __syncthreads(); __syncthreads(); continue; }  // keep barrier parity

        if (threadIdx.x == 0) { lsum = 0.0f; lss = 0.0f; }
        __syncthreads();

        // ---- sweep 1: sum / sumsq, 4 rows in flight per group ----
        float as0 = 0.0f, ass0 = 0.0f, as1 = 0.0f, ass1 = 0.0f;
        int r = s + grp;
        for (; r + 3 * ngrp < e; r += 4 * ngrp) {
            const f4 v0 = LOADX(r);
            const f4 v1 = LOADX(r + ngrp);
            const f4 v2 = LOADX(r + 2 * ngrp);
            const f4 v3 = LOADX(r + 3 * ngrp);
            as0 += v0.x + v0.y + v0.z + v0.w;
            ass0 = fmaf(v0.x, v0.x, fmaf(v0.y, v0.y, fmaf(v0.z, v0.z, fmaf(v0.w, v0.w, ass0))));
            as1 += v1.x + v1.y + v1.z + v1.w;
            ass1 = fmaf(v1.x, v1.x, fmaf(v1.y, v1.y, fmaf(v1.z, v1.z, fmaf(v1.w, v1.w, ass1))));
            as0 += v2.x + v2.y + v2.z + v2.w;
            ass0 = fmaf(v2.x, v2.x, fmaf(v2.y, v2.y, fmaf(v2.z, v2.z, fmaf(v2.w, v2.w, ass0))));
            as1 += v3.x + v3.y + v3.z + v3.w;
            ass1 = fmaf(v3.x, v3.x, fmaf(v3.y, v3.y, fmaf(v3.z, v3.z, fmaf(v3.w, v3.w, ass1))));
        }
        for (; r < e; r += ngrp) {
            const f4 v = LOADX(r);
            as0 += v.x + v.y + v.z + v.w;
            ass0 = fmaf(v.x, v.x, fmaf(v.y, v.y, fmaf(v.z, v.z, fmaf(v.w, v.w, ass0))));
        }
        float as = as0 + as1, ass = ass0 + ass1;
        #pragma unroll
        for (int off = 16; off > 0; off >>= 1) {
            as  += __shfl_down(as,  off, 32);
            ass += __shfl_down(ass, off, 32);
        }
        if (lane32 == 0) {
            atomicAdd(&lsum, as);
            atomicAdd(&lss,  ass);
        }
        __syncthreads();

        // stats: every thread computes redundantly (saves a barrier+broadcast)
        const float denom = (float)(e - s) * (float)NUM_FEAT;
        const float mean  = lsum / denom;
        const float var   = fmaxf(lss / denom - mean * mean, 0.0f);
        const float inv   = rsqrtf(var + EPS);

        // ---- sweep 2: normalize (x from L3, NT), 4 rows in flight ----
        r = s + grp;
        for (; r + 3 * ngrp < e; r += 4 * ngrp) {
            const f4 v0 = LOADX_NT(r);
            const f4 v1 = LOADX_NT(r + ngrp);
            const f4 v2 = LOADX_NT(r + 2 * ngrp);
            const f4 v3 = LOADX_NT(r + 3 * ngrp);
            f4 o0, o1, o2, o3;
            o0.x = fmaf(w.x, (v0.x - mean) * inv, b.x);
            o0.y = fmaf(w.y, (v0.y - mean) * inv, b.y);
            o0.z = fmaf(w.z, (v0.z - mean) * inv, b.z);
            o0.w = fmaf(w.w, (v0.w - mean) * inv, b.w);
            o1.x = fmaf(w.x, (v1.x - mean) * inv, b.x);
            o1.y = fmaf(w.y, (v1.y - mean) * inv, b.y);
            o1.z = fmaf(w.z, (v1.z - mean) * inv, b.z);
            o1.w = fmaf(w.w, (v1.w - mean) * inv, b.w);
            o2.x = fmaf(w.x, (v2.x - mean) * inv, b.x);
            o2.y = fmaf(w.y, (v2.y - mean) * inv, b.y);
            o2.z = fmaf(w.z, (v2.z - mean) * inv, b.z);
            o2.w = fmaf(w.w, (v2.w - mean) * inv, b.w);
            o3.x = fmaf(w.x, (v3.x - mean) * inv, b.x);
            o3.y = fmaf(w.y, (v3.y - mean) * inv, b.y);
            o3.z = fmaf(w.z, (v3.z - mean) * inv, b.z);
            o3.w = fmaf(w.w, (v3.w - mean) * inv, b.w);
            __builtin_nontemporal_store(o0, &reinterpret_cast<f4*>(out + (size_t)r * NUM_FEAT)[lane32]);
            __builtin_nontemporal_store(o1, &reinterpret_cast<f4*>(out + (size_t)(r + ngrp) * NUM_FEAT)[lane32]);
            __builtin_nontemporal_store(o2, &reinterpret_cast<f4*>(out + (size_t)(r + 2 * ngrp) * NUM_FEAT)[lane32]);
            __builtin_nontemporal_store(o3, &reinterpret_cast<f4*>(out + (size_t)(r + 3 * ngrp) * NUM_FEAT)[lane32]);
        }
        for (; r < e; r += ngrp) {
            const f4 v = LOADX_NT(r);
            f4 o;
            o.x = fmaf(w.x, (v.x - mean) * inv, b.x);
            o.y = fmaf(w.y, (v.y - mean) * inv, b.y);
            o.z = fmaf(w.z, (v.z - mean) * inv, b.z);
            o.w = fmaf(w.w, (v.w - mean) * inv, b.w);
            __builtin_nontemporal_store(o, &reinterpret_cast<f4*>(out + (size_t)r * NUM_FEAT)[lane32]);
        }
        __syncthreads();  // protect lsum/lss reset of next graph
    }
}

extern "C" void kernel_launch(void* const* d_in, const int* in_sizes, int n_in,
                              void* d_out, int out_size, void* d_ws, size_t ws_size,
                              hipStream_t stream) {
    const float* x      = (const float*)d_in[0];
    const int*   batch  = (const int*)d_in[1];
    const float* weight = (const float*)d_in[2];
    const float* bias   = (const float*)d_in[3];
    float* out = (float*)d_out;

    const int n_rows = in_sizes[1];  // NUM_NODES

    int* gstart = (int*)d_ws;
    int* gend   = gstart + NUM_GRAPHS;

    init_bounds_kernel<<<(NUM_GRAPHS + 255) / 256, 256, 0, stream>>>(gstart, gend);
    find_bounds_kernel<<<(n_rows + 255) / 256, 256, 0, stream>>>(batch, n_rows,
                                                                 gstart, gend);
    fused_kernel<<<NB, BT, 0, stream>>>(x, weight, bias, gstart, gend, out);
}